// Round 4
// baseline (709.357 us; speedup 1.0000x reference)
//
#include <hip/hip_runtime.h>
#include <hip/hip_bf16.h>

#define HH 50
#define TT 1024
#define BT 16            // batch tile per block (MFMA M)
#define NB (2048 / BT)   // 128 blocks
#define CHUNK 256        // x staging chunk (timesteps)
#define XST 260          // x LDS row stride (floats)
#define HST 72           // h LDS row stride (bf16 elems)

#define L2E 1.4426950408889634f   // log2(e)
#define K2E 2.8853900817779268f   // 2*log2(e)

typedef __bf16 bf16x8 __attribute__((ext_vector_type(8)));
typedef float f32x4 __attribute__((ext_vector_type(4)));

union BF8 { bf16x8 v; unsigned short u[8]; };

__device__ __forceinline__ unsigned short f2bf(float f) {
    unsigned int u = __builtin_bit_cast(unsigned int, f);
    u += 0x7fffu + ((u >> 16) & 1u);   // RNE
    return (unsigned short)(u >> 16);
}
__device__ __forceinline__ float rcp_f(float x) { return __builtin_amdgcn_rcpf(x); }
__device__ __forceinline__ float exp2_f(float x) { return __builtin_amdgcn_exp2f(x); }
__device__ __forceinline__ float sigm(float x) { return rcp_f(1.0f + __expf(-x)); }
__device__ __forceinline__ float tanh_f(float x) {
    return __builtin_fmaf(-2.0f, rcp_f(1.0f + __expf(2.0f * x)), 1.0f);
}

__global__ __launch_bounds__(512) void lstm_mfma_kernel(
    const float* __restrict__ x,
    const float* __restrict__ wih1, const float* __restrict__ whh1,
    const float* __restrict__ bih1, const float* __restrict__ bhh1,
    const float* __restrict__ wih2,
    const float* __restrict__ bih2, const float* __restrict__ bhh2,
    const float* __restrict__ fcw,  const float* __restrict__ fcb,
    float* __restrict__ out)
{
    __shared__ float xs[BT * XST];                 // 16.6 KB
    __shared__ unsigned short hb[2][BT * HST];     // 4.6 KB
    __shared__ float h2s[BT * 52];                 // 3.3 KB

    const int tid  = threadIdx.x;
    const int wv   = tid >> 6;        // 0..7
    const int lane = tid & 63;
    const int l16  = lane & 15;
    const int quad = lane >> 4;
    const int jt   = wv & 3;          // j-tile (both copies cover tiles 0..3)
    const int cp   = wv >> 2;         // copy: 0 -> rows {0,1}, 1 -> rows {2,3}
    const int j    = jt * 16 + l16;   // padded gate sub-index 0..63
    const bool jv  = (j < HH);
    const int b0   = blockIdx.x * BT;

    // gate scale folding: exp(a) terms become exp2(acc) directly
    //   i,f,o rows scaled by -log2e  (A = e^{-a} = exp2(acc'))
    //   g row scaled by +2*log2e     (G = e^{2a} = exp2(acc'))
    const float gsc[4] = { -L2E, -L2E, K2E, -L2E };

    // ---- persistent per-lane weights: Whh B-frags (bf16, pre-scaled) ----
    BF8 bw[4][2];
    float wihS[4], biasS[4];
    #pragma unroll
    for (int t4 = 0; t4 < 4; ++t4) {
        const int row = t4 * HH + j;
        const float s = gsc[t4];
        #pragma unroll
        for (int kk = 0; kk < 2; ++kk)
            #pragma unroll
            for (int e = 0; e < 8; ++e) {
                const int k = kk * 32 + quad * 8 + e;
                bw[t4][kk].u[e] = f2bf((jv && k < HH) ? s * whh1[row * HH + k] : 0.0f);
            }
        wihS[t4]  = jv ? s * wih1[row] : 0.0f;
        biasS[t4] = jv ? s * (bih1[row] + bhh1[row]) : 0.0f;
    }

    for (int i = tid; i < BT * HST; i += 512) hb[0][i] = 0;

    float cA = 0.f, cB = 0.f;         // c' = 2*log2e * c for rows 2cp, 2cp+1
    unsigned short* cur = hb[0];
    unsigned short* nxt = hb[1];

    const int r0 = 2 * cp, r1 = 2 * cp + 1;

    for (int t = 0; t < TT; ++t) {
        if ((t & (CHUNK - 1)) == 0) {
            for (int i = tid; i < BT * (CHUNK / 4); i += 512) {
                const int r = i >> 6, c4 = i & 63;
                const float4 xv = ((const float4*)x)[((b0 + r) * TT + t) / 4 + c4];
                *(float4*)&xs[r * XST + c4 * 4] = xv;
            }
            __syncthreads();   // also covers hb[0] zeroing at t==0
        }
        const int tc = t & (CHUNK - 1);

        // A-frags for h_t (both copies read the same data - LDS broadcast)
        const bf16x8 a0 = *(const bf16x8*)&cur[l16 * HST + quad * 8];
        const bf16x8 a1 = *(const bf16x8*)&cur[l16 * HST + 32 + quad * 8];

        const float xv0 = xs[(quad * 4 + 0) * XST + tc];
        const float xv1 = xs[(quad * 4 + 1) * XST + tc];
        const float xv2 = xs[(quad * 4 + 2) * XST + tc];
        const float xv3 = xs[(quad * 4 + 3) * XST + tc];

        f32x4 acc[4];
        #pragma unroll
        for (int t4 = 0; t4 < 4; ++t4) {
            acc[t4][0] = __builtin_fmaf(xv0, wihS[t4], biasS[t4]);
            acc[t4][1] = __builtin_fmaf(xv1, wihS[t4], biasS[t4]);
            acc[t4][2] = __builtin_fmaf(xv2, wihS[t4], biasS[t4]);
            acc[t4][3] = __builtin_fmaf(xv3, wihS[t4], biasS[t4]);
        }
        #pragma unroll
        for (int t4 = 0; t4 < 4; ++t4) {
            acc[t4] = __builtin_amdgcn_mfma_f32_16x16x32_bf16(a0, bw[t4][0].v, acc[t4], 0, 0, 0);
            acc[t4] = __builtin_amdgcn_mfma_f32_16x16x32_bf16(a1, bw[t4][1].v, acc[t4], 0, 0, 0);
        }

        // elementwise: this copy handles rows r0, r1 only (no cross-wave dep)
        {
            const float A = exp2_f(acc[0][r0]);        // e^{-a_i}
            const float Fe = exp2_f(acc[1][r0]);       // e^{-a_f}
            const float G = exp2_f(acc[2][r0]);        // e^{2 a_g}
            const float p = (G - 1.0f) * rcp_f((1.0f + A) * (G + 1.0f));   // i*g
            const float f = rcp_f(1.0f + Fe);
            cA = __builtin_fmaf(f, cA, K2E * p);
            cA = fminf(cA, 80.0f);                     // inf guard
            const float E = exp2_f(cA);                // e^{2c}
            const float Oe = exp2_f(acc[3][r0]);       // e^{-a_o}
            nxt[(quad * 4 + r0) * HST + j] =
                f2bf((E - 1.0f) * rcp_f((E + 1.0f) * (1.0f + Oe)));
        }
        {
            const float A = exp2_f(acc[0][r1]);
            const float Fe = exp2_f(acc[1][r1]);
            const float G = exp2_f(acc[2][r1]);
            const float p = (G - 1.0f) * rcp_f((1.0f + A) * (G + 1.0f));
            const float f = rcp_f(1.0f + Fe);
            cB = __builtin_fmaf(f, cB, K2E * p);
            cB = fminf(cB, 80.0f);
            const float E = exp2_f(cB);
            const float Oe = exp2_f(acc[3][r1]);
            nxt[(quad * 4 + r1) * HST + j] =
                f2bf((E - 1.0f) * rcp_f((E + 1.0f) * (1.0f + Oe)));
        }

        unsigned short* tmp = cur; cur = nxt; nxt = tmp;
        __syncthreads();
    }

    // ---- LSTM2 (one step from zero state), waves 0-3 only ----
    if (cp == 0) {
        BF8 bw2[4][2];
        float bias2S[4];
        #pragma unroll
        for (int t4 = 0; t4 < 4; ++t4) {
            const int row = t4 * HH + j;
            #pragma unroll
            for (int kk = 0; kk < 2; ++kk)
                #pragma unroll
                for (int e = 0; e < 8; ++e) {
                    const int k = kk * 32 + quad * 8 + e;
                    bw2[t4][kk].u[e] = f2bf((jv && k < HH) ? wih2[row * HH + k] : 0.0f);
                }
            bias2S[t4] = jv ? (bih2[row] + bhh2[row]) : 0.0f;
        }
        const bf16x8 a0 = *(const bf16x8*)&cur[l16 * HST + quad * 8];
        const bf16x8 a1 = *(const bf16x8*)&cur[l16 * HST + 32 + quad * 8];
        f32x4 acc2[4];
        #pragma unroll
        for (int t4 = 0; t4 < 4; ++t4) {
            acc2[t4][0] = bias2S[t4]; acc2[t4][1] = bias2S[t4];
            acc2[t4][2] = bias2S[t4]; acc2[t4][3] = bias2S[t4];
        }
        #pragma unroll
        for (int t4 = 0; t4 < 4; ++t4) {
            acc2[t4] = __builtin_amdgcn_mfma_f32_16x16x32_bf16(a0, bw2[t4][0].v, acc2[t4], 0, 0, 0);
            acc2[t4] = __builtin_amdgcn_mfma_f32_16x16x32_bf16(a1, bw2[t4][1].v, acc2[t4], 0, 0, 0);
        }
        #pragma unroll
        for (int r = 0; r < 4; ++r) {
            const float i2 = sigm(acc2[0][r]);
            const float g2 = tanh_f(acc2[2][r]);
            const float o2 = sigm(acc2[3][r]);
            const float cc = i2 * g2;           // f*c0 vanishes (c0 = 0)
            if (jv) h2s[(quad * 4 + r) * 52 + j] = o2 * tanh_f(cc);
        }
    }
    __syncthreads();

    // ---- FC: out[b] = h2[b] . fcW + fcb ----
    if (tid < 256) {
        const int b = tid >> 4, l = tid & 15;
        float p = 0.f;
        for (int jj = l; jj < HH; jj += 16)
            p = __builtin_fmaf(h2s[b * 52 + jj], fcw[jj], p);
        #pragma unroll
        for (int off = 8; off > 0; off >>= 1) p += __shfl_xor(p, off, 16);
        if (l == 0) out[b0 + b] = p + fcb[0];
    }
}

extern "C" void kernel_launch(void* const* d_in, const int* in_sizes, int n_in,
                              void* d_out, int out_size, void* d_ws, size_t ws_size,
                              hipStream_t stream) {
    lstm_mfma_kernel<<<NB, 512, 0, stream>>>(
        (const float*)d_in[0],
        (const float*)d_in[1], (const float*)d_in[2],
        (const float*)d_in[3], (const float*)d_in[4],
        (const float*)d_in[5],
        (const float*)d_in[7], (const float*)d_in[8],
        (const float*)d_in[9], (const float*)d_in[10],
        (float*)d_out);
}

// Round 5
// 663.086 us; speedup vs baseline: 1.0698x; 1.0698x over previous
//
#include <hip/hip_runtime.h>
#include <hip/hip_bf16.h>

#define HH 50
#define TT 1024
#define BT 16            // batch tile per block (MFMA M)
#define NB (2048 / BT)   // 128 blocks
#define CHUNK 256        // x staging chunk (timesteps)
#define CM (CHUNK - 1)
#define XST 260          // x LDS row stride (floats)
#define HST 72           // h LDS row stride (bf16 elems)

#define L2E 1.4426950408889634f   // log2(e)
#define K2E 2.8853900817779268f   // 2*log2(e)

typedef __bf16 bf16x8 __attribute__((ext_vector_type(8)));
typedef float f32x4 __attribute__((ext_vector_type(4)));

union BF8 { bf16x8 v; unsigned short u[8]; };

__device__ __forceinline__ unsigned short f2bf(float f) {
    unsigned int u = __builtin_bit_cast(unsigned int, f);
    u += 0x7fffu + ((u >> 16) & 1u);   // RNE
    return (unsigned short)(u >> 16);
}
__device__ __forceinline__ float rcp_f(float x) { return __builtin_amdgcn_rcpf(x); }
__device__ __forceinline__ float exp2_f(float x) { return __builtin_amdgcn_exp2f(x); }
__device__ __forceinline__ float sigm(float x) { return rcp_f(1.0f + __expf(-x)); }
__device__ __forceinline__ float tanh_f(float x) {
    return __builtin_fmaf(-2.0f, rcp_f(1.0f + __expf(2.0f * x)), 1.0f);
}

// __launch_bounds__(256, 1): 1 block/CU is plenty (path-latency-bound, not
// occupancy-bound) -> let the allocator use VGPRs freely for ILP.
__global__ __launch_bounds__(256, 1) void lstm_mfma_kernel(
    const float* __restrict__ x,
    const float* __restrict__ wih1, const float* __restrict__ whh1,
    const float* __restrict__ bih1, const float* __restrict__ bhh1,
    const float* __restrict__ wih2,
    const float* __restrict__ bih2, const float* __restrict__ bhh2,
    const float* __restrict__ fcw,  const float* __restrict__ fcb,
    float* __restrict__ out)
{
    __shared__ float xs[BT * XST];                 // 16.6 KB
    __shared__ unsigned short hb[2][BT * HST];     // 4.6 KB
    __shared__ float h2s[BT * 52];                 // 3.3 KB

    const int tid  = threadIdx.x;
    const int wv   = tid >> 6;        // 0..3 = j-tile
    const int lane = tid & 63;
    const int l16  = lane & 15;
    const int quad = lane >> 4;
    const int j    = wv * 16 + l16;   // padded gate sub-index 0..63
    const bool jv  = (j < HH);
    const int b0   = blockIdx.x * BT;

    // gate scale folding: exp(a) terms become exp2(acc) directly
    //   i,f,o rows scaled by -log2e  (A = e^{-a} = exp2(acc'))
    //   g row scaled by +2*log2e     (G = e^{2a} = exp2(acc'))
    const float gsc[4] = { -L2E, -L2E, K2E, -L2E };

    // ---- persistent per-lane weights: Whh B-frags (bf16, pre-scaled) ----
    BF8 bw[4][2];
    float wihS[4], biasS[4];
    #pragma unroll
    for (int t4 = 0; t4 < 4; ++t4) {
        const int row = t4 * HH + j;
        const float s = gsc[t4];
        #pragma unroll
        for (int kk = 0; kk < 2; ++kk)
            #pragma unroll
            for (int e = 0; e < 8; ++e) {
                const int k = kk * 32 + quad * 8 + e;
                bw[t4][kk].u[e] = f2bf((jv && k < HH) ? s * whh1[row * HH + k] : 0.0f);
            }
        wihS[t4]  = jv ? s * wih1[row] : 0.0f;
        biasS[t4] = jv ? s * (bih1[row] + bhh1[row]) : 0.0f;
    }

    for (int i = tid; i < BT * HST; i += 256) hb[0][i] = 0;

    float c0 = 0.f, c1 = 0.f, c2 = 0.f, c3 = 0.f;   // c' = 2*log2e * c
    unsigned short* cur = hb[0];
    unsigned short* nxt = hb[1];

    const f32x4 zed = {0.f, 0.f, 0.f, 0.f};         // loop-invariant C for accB
    f32x4 iv[4];                                    // pre-computed x*wih+bias

    for (int t = 0; t < TT; ++t) {
        if ((t & CM) == 0) {
            // stage chunk (prev-chunk reads all completed before last barrier)
            for (int i = tid; i < BT * (CHUNK / 4); i += 256) {
                const int r = i >> 6, c4 = i & 63;
                const float4 xv = ((const float4*)x)[((b0 + r) * TT + t) / 4 + c4];
                *(float4*)&xs[r * XST + c4 * 4] = xv;
            }
            __syncthreads();   // xs visible (covers hb zeroing at t==0)
            {
                const float xv0 = xs[(quad * 4 + 0) * XST + 0];
                const float xv1 = xs[(quad * 4 + 1) * XST + 0];
                const float xv2 = xs[(quad * 4 + 2) * XST + 0];
                const float xv3 = xs[(quad * 4 + 3) * XST + 0];
                #pragma unroll
                for (int t4 = 0; t4 < 4; ++t4) {
                    iv[t4][0] = __builtin_fmaf(xv0, wihS[t4], biasS[t4]);
                    iv[t4][1] = __builtin_fmaf(xv1, wihS[t4], biasS[t4]);
                    iv[t4][2] = __builtin_fmaf(xv2, wihS[t4], biasS[t4]);
                    iv[t4][3] = __builtin_fmaf(xv3, wihS[t4], biasS[t4]);
                }
            }
        }

        // A-frags for h_t
        const bf16x8 a0 = *(const bf16x8*)&cur[l16 * HST + quad * 8];
        const bf16x8 a1 = *(const bf16x8*)&cur[l16 * HST + 32 + quad * 8];

        // split-C: two INDEPENDENT MFMAs per gate type, summed after
        f32x4 accA[4], accB[4], acc[4];
        #pragma unroll
        for (int t4 = 0; t4 < 4; ++t4)
            accA[t4] = __builtin_amdgcn_mfma_f32_16x16x32_bf16(a0, bw[t4][0].v, iv[t4], 0, 0, 0);
        #pragma unroll
        for (int t4 = 0; t4 < 4; ++t4)
            accB[t4] = __builtin_amdgcn_mfma_f32_16x16x32_bf16(a1, bw[t4][1].v, zed, 0, 0, 0);
        #pragma unroll
        for (int t4 = 0; t4 < 4; ++t4)
            acc[t4] = accA[t4] + accB[t4];

        // elementwise: lane holds i,f,g,o for (b=quad*4+r, j)
        {
            const float A  = exp2_f(acc[0][0]);        // e^{-a_i}
            const float Fe = exp2_f(acc[1][0]);        // e^{-a_f}
            const float G  = exp2_f(acc[2][0]);        // e^{2 a_g}
            const float Oe = exp2_f(acc[3][0]);        // e^{-a_o}
            const float p  = (G - 1.0f) * rcp_f((1.0f + A) * (G + 1.0f));
            const float f  = rcp_f(1.0f + Fe);
            c0 = fminf(__builtin_fmaf(f, c0, K2E * p), 80.0f);
            const float E  = exp2_f(c0);
            nxt[(quad * 4 + 0) * HST + j] =
                f2bf((E - 1.0f) * rcp_f((E + 1.0f) * (1.0f + Oe)));
        }
        {
            const float A  = exp2_f(acc[0][1]);
            const float Fe = exp2_f(acc[1][1]);
            const float G  = exp2_f(acc[2][1]);
            const float Oe = exp2_f(acc[3][1]);
            const float p  = (G - 1.0f) * rcp_f((1.0f + A) * (G + 1.0f));
            const float f  = rcp_f(1.0f + Fe);
            c1 = fminf(__builtin_fmaf(f, c1, K2E * p), 80.0f);
            const float E  = exp2_f(c1);
            nxt[(quad * 4 + 1) * HST + j] =
                f2bf((E - 1.0f) * rcp_f((E + 1.0f) * (1.0f + Oe)));
        }
        {
            const float A  = exp2_f(acc[0][2]);
            const float Fe = exp2_f(acc[1][2]);
            const float G  = exp2_f(acc[2][2]);
            const float Oe = exp2_f(acc[3][2]);
            const float p  = (G - 1.0f) * rcp_f((1.0f + A) * (G + 1.0f));
            const float f  = rcp_f(1.0f + Fe);
            c2 = fminf(__builtin_fmaf(f, c2, K2E * p), 80.0f);
            const float E  = exp2_f(c2);
            nxt[(quad * 4 + 2) * HST + j] =
                f2bf((E - 1.0f) * rcp_f((E + 1.0f) * (1.0f + Oe)));
        }
        {
            const float A  = exp2_f(acc[0][3]);
            const float Fe = exp2_f(acc[1][3]);
            const float G  = exp2_f(acc[2][3]);
            const float Oe = exp2_f(acc[3][3]);
            const float p  = (G - 1.0f) * rcp_f((1.0f + A) * (G + 1.0f));
            const float f  = rcp_f(1.0f + Fe);
            c3 = fminf(__builtin_fmaf(f, c3, K2E * p), 80.0f);
            const float E  = exp2_f(c3);
            nxt[(quad * 4 + 3) * HST + j] =
                f2bf((E - 1.0f) * rcp_f((E + 1.0f) * (1.0f + Oe)));
        }

        // SW-pipeline: pre-compute next step's init (xs-only, off the h path)
        const int tn = (t + 1) & CM;
        if (tn != 0) {
            const float xv0 = xs[(quad * 4 + 0) * XST + tn];
            const float xv1 = xs[(quad * 4 + 1) * XST + tn];
            const float xv2 = xs[(quad * 4 + 2) * XST + tn];
            const float xv3 = xs[(quad * 4 + 3) * XST + tn];
            #pragma unroll
            for (int t4 = 0; t4 < 4; ++t4) {
                iv[t4][0] = __builtin_fmaf(xv0, wihS[t4], biasS[t4]);
                iv[t4][1] = __builtin_fmaf(xv1, wihS[t4], biasS[t4]);
                iv[t4][2] = __builtin_fmaf(xv2, wihS[t4], biasS[t4]);
                iv[t4][3] = __builtin_fmaf(xv3, wihS[t4], biasS[t4]);
            }
        }

        unsigned short* tmp = cur; cur = nxt; nxt = tmp;
        __syncthreads();
    }

    // ---- LSTM2 (one step from zero state) ----
    {
        BF8 bw2[4][2];
        float bias2S[4];
        #pragma unroll
        for (int t4 = 0; t4 < 4; ++t4) {
            const int row = t4 * HH + j;
            #pragma unroll
            for (int kk = 0; kk < 2; ++kk)
                #pragma unroll
                for (int e = 0; e < 8; ++e) {
                    const int k = kk * 32 + quad * 8 + e;
                    bw2[t4][kk].u[e] = f2bf((jv && k < HH) ? wih2[row * HH + k] : 0.0f);
                }
            bias2S[t4] = jv ? (bih2[row] + bhh2[row]) : 0.0f;
        }
        const bf16x8 a0 = *(const bf16x8*)&cur[l16 * HST + quad * 8];
        const bf16x8 a1 = *(const bf16x8*)&cur[l16 * HST + 32 + quad * 8];
        f32x4 acc2[4];
        #pragma unroll
        for (int t4 = 0; t4 < 4; ++t4) {
            acc2[t4][0] = bias2S[t4]; acc2[t4][1] = bias2S[t4];
            acc2[t4][2] = bias2S[t4]; acc2[t4][3] = bias2S[t4];
        }
        #pragma unroll
        for (int t4 = 0; t4 < 4; ++t4) {
            acc2[t4] = __builtin_amdgcn_mfma_f32_16x16x32_bf16(a0, bw2[t4][0].v, acc2[t4], 0, 0, 0);
            acc2[t4] = __builtin_amdgcn_mfma_f32_16x16x32_bf16(a1, bw2[t4][1].v, acc2[t4], 0, 0, 0);
        }
        #pragma unroll
        for (int r = 0; r < 4; ++r) {
            const float i2 = sigm(acc2[0][r]);
            const float g2 = tanh_f(acc2[2][r]);
            const float o2 = sigm(acc2[3][r]);
            const float cc = i2 * g2;           // f*c0 vanishes (c0 = 0)
            if (jv) h2s[(quad * 4 + r) * 52 + j] = o2 * tanh_f(cc);
        }
    }
    __syncthreads();

    // ---- FC: out[b] = h2[b] . fcW + fcb ----
    {
        const int b = tid >> 4, l = tid & 15;
        float p = 0.f;
        for (int jj = l; jj < HH; jj += 16)
            p = __builtin_fmaf(h2s[b * 52 + jj], fcw[jj], p);
        #pragma unroll
        for (int off = 8; off > 0; off >>= 1) p += __shfl_xor(p, off, 16);
        if (l == 0) out[b0 + b] = p + fcb[0];
    }
}

extern "C" void kernel_launch(void* const* d_in, const int* in_sizes, int n_in,
                              void* d_out, int out_size, void* d_ws, size_t ws_size,
                              hipStream_t stream) {
    lstm_mfma_kernel<<<NB, 256, 0, stream>>>(
        (const float*)d_in[0],
        (const float*)d_in[1], (const float*)d_in[2],
        (const float*)d_in[3], (const float*)d_in[4],
        (const float*)d_in[5],
        (const float*)d_in[7], (const float*)d_in[8],
        (const float*)d_in[9], (const float*)d_in[10],
        (float*)d_out);
}